// Round 4
// baseline (73.021 us; speedup 1.0000x reference)
//
#include <hip/hip_runtime.h>

typedef float v2f __attribute__((ext_vector_type(2)));

#define DEV static __device__ __forceinline__

// xor16 across the 16-lane rows of a 32-lane group (LDS pipe)
DEV float swz_xor16(float v) {
  return __int_as_float(__builtin_amdgcn_ds_swizzle(__float_as_int(v), 0x401F));
}

// one fused dpp-add line for operand n
#define DL(n, ctrl) \
  "v_add_f32_dpp %" #n ", %" #n ", %" #n " " ctrl " row_mask:0xf bank_mask:0xf\n\t"

#define ST16(c) DL(0,c) DL(1,c) DL(2,c) DL(3,c) DL(4,c) DL(5,c) DL(6,c) DL(7,c) \
                DL(8,c) DL(9,c) DL(10,c) DL(11,c) DL(12,c) DL(13,c) DL(14,c) DL(15,c)
#define ST8(c)  DL(0,c) DL(1,c) DL(2,c) DL(3,c) DL(4,c) DL(5,c) DL(6,c) DL(7,c)

// 16 interleaved butterfly chains, 4 DPP stages each (xor1,xor2,~xor4,~xor8).
// Interleaving distance 16 >> 2-cycle VALU->DPP hazard; s_nop 1 guards entry
// (the adds feeding these regs may be scheduled immediately before the asm).
DEV void dpp4x16(float& r0, float& r1, float& r2, float& r3,
                 float& r4, float& r5, float& r6, float& r7,
                 float& r8, float& r9, float& r10, float& r11,
                 float& r12, float& r13, float& r14, float& r15) {
  asm("s_nop 1\n\t"
      ST16("quad_perm:[1,0,3,2]")
      ST16("quad_perm:[2,3,0,1]")
      ST16("row_half_mirror")
      ST16("row_mirror")
      : "+v"(r0), "+v"(r1), "+v"(r2), "+v"(r3),
        "+v"(r4), "+v"(r5), "+v"(r6), "+v"(r7),
        "+v"(r8), "+v"(r9), "+v"(r10), "+v"(r11),
        "+v"(r12), "+v"(r13), "+v"(r14), "+v"(r15));
}

DEV void dpp4x8(float& r0, float& r1, float& r2, float& r3,
                float& r4, float& r5, float& r6, float& r7) {
  asm("s_nop 1\n\t"
      ST8("quad_perm:[1,0,3,2]")
      ST8("quad_perm:[2,3,0,1]")
      ST8("row_half_mirror")
      ST8("row_mirror")
      : "+v"(r0), "+v"(r1), "+v"(r2), "+v"(r3),
        "+v"(r4), "+v"(r5), "+v"(r6), "+v"(r7));
}

// DPP move with bound_ctrl (OOB -> 0); compiler-managed hazards.
template<int CTRL>
DEV float dpp_movf(float v) {
  return __int_as_float(__builtin_amdgcn_update_dpp(
      0, __float_as_int(v), CTRL, 0xF, 0xF, true));
}

// packed gelu (tanh form): x*sigmoid(1.5957691*(x+0.044715x^3));
// z = -1.5957691216*log2(e) = -2.3022081; |err| < ~1e-3
DEV v2f gelu2(v2f x) {
  v2f x2 = x * x;
  v2f t  = x * (x2 * 0.044715f + 1.0f);
  v2f z  = t * -2.3022081f;
  v2f e  = { __builtin_amdgcn_exp2f(z.x), __builtin_amdgcn_exp2f(z.y) };
  v2f den = e + 1.0f;
  v2f r  = { __builtin_amdgcn_rcpf(den.x), __builtin_amdgcn_rcpf(den.y) };
  return x * r;
}

__global__ void __launch_bounds__(256) gmlp_fused(
    const float* __restrict__ x,
    const float* __restrict__ ln1_g, const float* __restrict__ ln1_b,
    const float* __restrict__ W1, const float* __restrict__ b1,
    const float* __restrict__ sgu_g, const float* __restrict__ sgu_b,
    const float* __restrict__ conv_w, const float* __restrict__ conv_b,
    const float* __restrict__ W2, const float* __restrict__ b2,
    float* __restrict__ out, int nsamp)
{
  const int pos = threadIdx.x & 31;
  const int grp = threadIdx.x >> 5;
  const int gpb = blockDim.x >> 5;

  const float g1 = ln1_g[pos], be1 = ln1_b[pos];
  const float g2 = sgu_g[pos], be2 = sgu_b[pos];
  const v2f g1v = { g1, g1 }, b1v = { be1, be1 };
  const v2f g2v = { g2, g2 }, b2v = { be2, be2 };

  const float fm1 = (pos >= 1) ? 1.0f : 0.0f;
  const float fm2 = (pos >= 2) ? 1.0f : 0.0f;
  const float fp1 = (pos <= 30) ? 1.0f : 0.0f;
  const float fp2 = (pos <= 29) ? 1.0f : 0.0f;
  const v2f mm1 = { fm1, fm1 }, mm2 = { fm2, fm2 };
  const v2f mp1 = { fp1, fp1 }, mp2 = { fp2, fp2 };

  const v2f* __restrict__ W1v = (const v2f*)W1;   // W1v[o*4+p]
  const v2f* __restrict__ W2v = (const v2f*)W2;   // W2v[o*2+p]

  int s = blockIdx.x * gpb + grp;
  const int sstep = gridDim.x * gpb;

  // ---- prologue load (clamped so idle groups stay in-bounds) ----
  float cx[8];
  {
    int s0 = s < nsamp ? s : (nsamp - 1);
    const float* xs = x + (size_t)s0 * 256 + pos;
#pragma unroll
    for (int c = 0; c < 8; ++c) cx[c] = xs[c * 32];
  }

  for (; s < nsamp; s += sstep) {
    // ---- prefetch next iteration's sample (clamped; discarded on exit) ----
    int sn = s + sstep; sn = (sn < nsamp) ? sn : s;
    const float* xn = x + (size_t)sn * 256 + pos;
    float nx[8];
#pragma unroll
    for (int c = 0; c < 8; ++c) nx[c] = xn[c * 32];

    v2f res2[4];
#pragma unroll
    for (int p = 0; p < 4; ++p) res2[p] = v2f{ cx[2*p], cx[2*p+1] };

    // ---- LN1: 16 chains (8 ch x {sum, sumsq}) batched ----
    float r[16], t[16];
#pragma unroll
    for (int p = 0; p < 4; ++p) {
      v2f sq = res2[p] * res2[p];
      r[2*p]   = res2[p].x; r[2*p+1] = res2[p].y;
      r[8+2*p] = sq.x;      r[9+2*p] = sq.y;
    }
#pragma unroll
    for (int i = 0; i < 16; ++i) t[i] = swz_xor16(r[i]);
#pragma unroll
    for (int i = 0; i < 16; ++i) r[i] += t[i];
    dpp4x16(r[0], r[1], r[2], r[3], r[4], r[5], r[6], r[7],
            r[8], r[9], r[10], r[11], r[12], r[13], r[14], r[15]);

    v2f h[4];
#pragma unroll
    for (int p = 0; p < 4; ++p) {
      v2f s1 = { r[2*p], r[2*p+1] }, s2 = { r[8+2*p], r[9+2*p] };
      v2f mu  = s1 * 0.03125f;
      v2f var = s2 * 0.03125f - mu * mu;
      v2f ve  = var + 1e-5f;
      v2f rs  = { __builtin_amdgcn_rsqf(ve.x), __builtin_amdgcn_rsqf(ve.y) };
      v2f A = rs * g1v;
      v2f B = b1v - mu * A;
      h[p] = res2[p] * A + B;
    }

    // ---- channel-mix matmul (8x8) packed + bias ----
    float uo[8];
#pragma unroll
    for (int o = 0; o < 8; ++o) {
      v2f acc = h[0] * W1v[o*4 + 0];
      acc = h[1] * W1v[o*4 + 1] + acc;
      acc = h[2] * W1v[o*4 + 2] + acc;
      acc = h[3] * W1v[o*4 + 3] + acc;
      uo[o] = acc.x + acc.y + b1[o];
    }
    v2f t01 = gelu2(v2f{ uo[0], uo[1] });
    v2f t23 = gelu2(v2f{ uo[2], uo[3] });
    v2f t45 = gelu2(v2f{ uo[4], uo[5] });
    v2f t67 = gelu2(v2f{ uo[6], uo[7] });

    // ---- SGU LN2: 8 chains (4 ch x {sum, sumsq}) batched ----
    float q[8], tq[8];
    {
      v2f sq0 = t45 * t45, sq1 = t67 * t67;
      q[0] = t45.x; q[1] = t45.y; q[2] = t67.x; q[3] = t67.y;
      q[4] = sq0.x; q[5] = sq0.y; q[6] = sq1.x; q[7] = sq1.y;
    }
#pragma unroll
    for (int i = 0; i < 8; ++i) tq[i] = swz_xor16(q[i]);
#pragma unroll
    for (int i = 0; i < 8; ++i) q[i] += tq[i];
    dpp4x8(q[0], q[1], q[2], q[3], q[4], q[5], q[6], q[7]);

    v2f vl[2];
#pragma unroll
    for (int p = 0; p < 2; ++p) {
      v2f val = (p == 0) ? t45 : t67;
      v2f s1 = { q[2*p], q[2*p+1] }, s2 = { q[4+2*p], q[5+2*p] };
      v2f mu  = s1 * 0.03125f;
      v2f var = s2 * 0.03125f - mu * mu;
      v2f ve  = var + 1e-5f;
      v2f rs  = { __builtin_amdgcn_rsqf(ve.x), __builtin_amdgcn_rsqf(ve.y) };
      v2f A = rs * g2v;
      v2f B = b2v - mu * A;
      vl[p] = val * A + B;
    }

    // ---- conv taps via DPP wave shifts, masked ----
    v2f cm1[2], cm2[2], cp1[2], cp2[2];
#pragma unroll
    for (int p = 0; p < 2; ++p) {
      v2f a = v2f{ dpp_movf<0x138>(vl[p].x),  dpp_movf<0x138>(vl[p].y)  } * mm1; // pos-1
      cm1[p] = a;
      cm2[p] = v2f{ dpp_movf<0x138>(a.x),     dpp_movf<0x138>(a.y)      } * mm2; // pos-2
      v2f d = v2f{ dpp_movf<0x130>(vl[p].x),  dpp_movf<0x130>(vl[p].y)  } * mp1; // pos+1
      cp1[p] = d;
      cp2[p] = v2f{ dpp_movf<0x130>(d.x),     dpp_movf<0x130>(d.y)      } * mp2; // pos+2
    }

    // ---- conv (4 out, 4 in, 5 taps) + bias, gate with u ----
    const float uu[4] = { t01.x, t01.y, t23.x, t23.y };
    float gte[4];
#pragma unroll
    for (int o = 0; o < 4; ++o) {
      float acc = conv_b[o];
#pragma unroll
      for (int c = 0; c < 4; ++c) {
        const float* w = conv_w + (o * 4 + c) * 5;
        float vm2 = (c & 1) ? cm2[c>>1].y : cm2[c>>1].x;
        float vm1 = (c & 1) ? cm1[c>>1].y : cm1[c>>1].x;
        float v0  = (c & 1) ? vl [c>>1].y : vl [c>>1].x;
        float vp1 = (c & 1) ? cp1[c>>1].y : cp1[c>>1].x;
        float vp2 = (c & 1) ? cp2[c>>1].y : cp2[c>>1].x;
        acc = __builtin_fmaf(vm2, w[0], acc);
        acc = __builtin_fmaf(vm1, w[1], acc);
        acc = __builtin_fmaf(v0,  w[2], acc);
        acc = __builtin_fmaf(vp1, w[3], acc);
        acc = __builtin_fmaf(vp2, w[4], acc);
      }
      gte[o] = uu[o] * acc;
    }

    // ---- out matmul (4->8) packed + gelu + residual, NT store ----
    const v2f gv0 = { gte[0], gte[1] }, gv1 = { gte[2], gte[3] };
    float oo[8];
#pragma unroll
    for (int o = 0; o < 8; ++o) {
      v2f acc = gv0 * W2v[o*2 + 0];
      acc = gv1 * W2v[o*2 + 1] + acc;
      oo[o] = acc.x + acc.y + b2[o];
    }
    float* os = out + (size_t)s * 256 + pos;
#pragma unroll
    for (int p = 0; p < 4; ++p) {
      v2f g = gelu2(v2f{ oo[2*p], oo[2*p+1] }) + res2[p];
      __builtin_nontemporal_store(g.x, os + (2*p)*32);
      __builtin_nontemporal_store(g.y, os + (2*p+1)*32);
    }

    // rotate prefetched registers
#pragma unroll
    for (int c = 0; c < 8; ++c) cx[c] = nx[c];
  }
}

extern "C" void kernel_launch(void* const* d_in, const int* in_sizes, int n_in,
                              void* d_out, int out_size, void* d_ws, size_t ws_size,
                              hipStream_t stream) {
  const float* x      = (const float*)d_in[0];
  const float* ln1_g  = (const float*)d_in[1];
  const float* ln1_b  = (const float*)d_in[2];
  const float* W1     = (const float*)d_in[3];
  const float* b1     = (const float*)d_in[4];
  const float* sgu_g  = (const float*)d_in[5];
  const float* sgu_b  = (const float*)d_in[6];
  const float* conv_w = (const float*)d_in[7];
  const float* conv_b = (const float*)d_in[8];
  const float* W2     = (const float*)d_in[9];
  const float* b2     = (const float*)d_in[10];
  float* out = (float*)d_out;

  int nsamp = in_sizes[0] / 256;
  int groups_needed = (nsamp + 7) / 8;
  int nblocks = groups_needed < 4096 ? groups_needed : 4096;
  if (nblocks < 1) nblocks = 1;

  hipLaunchKernelGGL(gmlp_fused, dim3(nblocks), dim3(256), 0, stream,
                     x, ln1_g, ln1_b, W1, b1, sgu_g, sgu_b,
                     conv_w, conv_b, W2, b2, out, nsamp);
}